// Round 2
// baseline (103.871 us; speedup 1.0000x reference)
//
#include <hip/hip_runtime.h>

#define DIM 512
#define BK 32

typedef unsigned int uint;
typedef unsigned short ushort;
typedef __attribute__((ext_vector_type(8))) short short8;
typedef __attribute__((ext_vector_type(4))) float f32x4;

// Pack two fp32 -> two bf16 (round-to-nearest-ish via +0x8000, then byte-perm pack).
__device__ __forceinline__ uint pack_bf16(float a, float b) {
    union { float f; uint u; } ua, ub;
    ua.f = a; ub.f = b;
    uint x0 = ua.u + 0x8000u;
    uint x1 = ub.u + 0x8000u;
    return __builtin_amdgcn_perm(x1, x0, 0x07060302);
}

// =====================================================================
// K1: fused   zconv (in B-staging) + diag + batched GEMM + LSE partials
// block = (a, rt): computes T[a, rt*128:(rt+1)*128, 0:256]
// 512 threads = 8 waves; wave (wr, wc) owns a 64x64 sub-tile (4x4 MFMA tiles)
// =====================================================================
__global__ void __launch_bounds__(512, 4)
gemm_fused(const float* __restrict__ x, const float* __restrict__ y,
           const float* __restrict__ z,
           float* __restrict__ rowM, float* __restrict__ rowS,
           float* __restrict__ colM, float* __restrict__ colS,
           float* __restrict__ diag, uint* __restrict__ counter) {
    __shared__ __align__(16) float xs[DIM];
    __shared__ __align__(16) ushort As[128 * BK];
    __shared__ __align__(16) ushort Bs[256 * BK];
    __shared__ float redA[128 * 4];
    __shared__ float rowMaxS[128];
    __shared__ float redB[256 * 2];
    __shared__ float colMaxS[256];
    __shared__ float dred[8];

    const int tid = threadIdx.x;
    const int a   = blockIdx.x >> 1;
    const int rt  = blockIdx.x & 1;

    if (blockIdx.x == 0 && tid == 0) *counter = 0u;   // reset K2's flag each call

    xs[tid] = x[a * DIM + tid];   // x[a,:] cached for the whole block

    const int lane = tid & 63;
    const int wave = tid >> 6;
    const int quad = lane >> 4;
    const int ln15 = lane & 15;
    const int wr = wave >> 2;     // 0..1  -> row offset wr*64
    const int wc = wave & 3;      // 0..3  -> col offset wc*64

    // ---- fused diag: T[a,a,a] exact fp32 (rt==0 blocks only; D==512==blockDim) ----
    if (rt == 0) {
        float p = xs[tid] * y[a * DIM + tid] * z[a * DIM + tid];
        #pragma unroll
        for (int m = 1; m < 64; m <<= 1) p += __shfl_xor(p, m, 64);
        if (lane == 0) dred[wave] = p;
        __syncthreads();
        if (tid == 0) {
            float s = 0.f;
            #pragma unroll
            for (int w2 = 0; w2 < 8; ++w2) s += dred[w2];
            diag[a] = s;
        }
    }

    f32x4 acc[4][4];
    #pragma unroll
    for (int i = 0; i < 4; ++i)
        #pragma unroll
        for (int j = 0; j < 4; ++j)
            acc[i][j] = (f32x4){0.f, 0.f, 0.f, 0.f};

    const int fA = tid * 8;        // A staging: 4096 bf16 elems, 8 per thread
    const int rA = fA >> 5;        // 0..127
    const int kA = fA & 31;        // 0,8,16,24
    const float* yrow = y + (rt * 128 + rA) * DIM + kA;

    const int fB = tid * 16;       // B staging: 8192 bf16 elems, 16 per thread
    const int sB = fB >> 5;        // 0..255
    const int kB = fB & 31;        // 0 or 16
    const float* zrow = z + sB * DIM + kB;

    for (int kt = 0; kt < DIM / BK; ++kt) {
        const int k0 = kt * BK;
        __syncthreads();
        // stage A = bf16(x[a,k] * y[r,k])
        {
            float4 y0 = *(const float4*)(yrow + k0);
            float4 y1 = *(const float4*)(yrow + k0 + 4);
            float4 x0 = *(const float4*)(xs + k0 + kA);
            float4 x1 = *(const float4*)(xs + k0 + kA + 4);
            uint4 o;
            o.x = pack_bf16(y0.x * x0.x, y0.y * x0.y);
            o.y = pack_bf16(y0.z * x0.z, y0.w * x0.w);
            o.z = pack_bf16(y1.x * x1.x, y1.y * x1.y);
            o.w = pack_bf16(y1.z * x1.z, y1.w * x1.w);
            *(uint4*)(As + fA) = o;
        }
        // stage B = bf16(z tile), converting fp32->bf16 in-kernel
        {
            float4 z0 = *(const float4*)(zrow + k0);
            float4 z1 = *(const float4*)(zrow + k0 + 4);
            float4 z2 = *(const float4*)(zrow + k0 + 8);
            float4 z3 = *(const float4*)(zrow + k0 + 12);
            uint4 o0, o1;
            o0.x = pack_bf16(z0.x, z0.y);
            o0.y = pack_bf16(z0.z, z0.w);
            o0.z = pack_bf16(z1.x, z1.y);
            o0.w = pack_bf16(z1.z, z1.w);
            o1.x = pack_bf16(z2.x, z2.y);
            o1.y = pack_bf16(z2.z, z2.w);
            o1.z = pack_bf16(z3.x, z3.y);
            o1.w = pack_bf16(z3.z, z3.w);
            *(uint4*)(Bs + fB) = o0;
            *(uint4*)(Bs + fB + 8) = o1;
        }
        __syncthreads();
        // fragments + MFMA
        short8 af[4], bfr[4];
        #pragma unroll
        for (int i = 0; i < 4; ++i)
            af[i] = *(const short8*)(As + (wr * 64 + i * 16 + ln15) * BK + quad * 8);
        #pragma unroll
        for (int j = 0; j < 4; ++j)
            bfr[j] = *(const short8*)(Bs + (wc * 64 + j * 16 + ln15) * BK + quad * 8);
        #pragma unroll
        for (int i = 0; i < 4; ++i)
            #pragma unroll
            for (int j = 0; j < 4; ++j)
                acc[i][j] = __builtin_amdgcn_mfma_f32_16x16x32_bf16(af[i], bfr[j], acc[i][j], 0, 0, 0);
    }
    __syncthreads();

    // ===== row-wise LSE partials (reduce over all 256 cols s) =====
    // lane owns rows r = wr*64 + i*16 + quad*4 + reg, cols n = wc*64 + j*16 + ln15
    #pragma unroll
    for (int i = 0; i < 4; ++i) {
        #pragma unroll
        for (int reg = 0; reg < 4; ++reg) {
            float m = fmaxf(fmaxf(acc[i][0][reg], acc[i][1][reg]),
                            fmaxf(acc[i][2][reg], acc[i][3][reg]));
            #pragma unroll
            for (int d = 1; d < 16; d <<= 1) m = fmaxf(m, __shfl_xor(m, d, 64));
            if (ln15 == 0) redA[(wr * 64 + i * 16 + quad * 4 + reg) * 4 + wc] = m;
        }
    }
    __syncthreads();
    if (tid < 128) {
        float m = fmaxf(fmaxf(redA[tid * 4 + 0], redA[tid * 4 + 1]),
                        fmaxf(redA[tid * 4 + 2], redA[tid * 4 + 3]));
        rowMaxS[tid] = m;
    }
    __syncthreads();
    #pragma unroll
    for (int i = 0; i < 4; ++i) {
        #pragma unroll
        for (int reg = 0; reg < 4; ++reg) {
            int r = wr * 64 + i * 16 + quad * 4 + reg;
            float rm = rowMaxS[r];
            float s = __expf(acc[i][0][reg] - rm) + __expf(acc[i][1][reg] - rm)
                    + __expf(acc[i][2][reg] - rm) + __expf(acc[i][3][reg] - rm);
            #pragma unroll
            for (int d = 1; d < 16; d <<= 1) s += __shfl_xor(s, d, 64);
            if (ln15 == 0) redA[r * 4 + wc] = s;
        }
    }
    __syncthreads();
    if (tid < 128) {
        float s = redA[tid * 4 + 0] + redA[tid * 4 + 1] + redA[tid * 4 + 2] + redA[tid * 4 + 3];
        int rg = rt * 128 + tid;
        rowM[a * 256 + rg] = rowMaxS[tid];
        rowS[a * 256 + rg] = s;
    }

    // ===== col-wise LSE partials (reduce over this block's 128 rows) =====
    #pragma unroll
    for (int j = 0; j < 4; ++j) {
        float m = -3.4e38f;
        #pragma unroll
        for (int i = 0; i < 4; ++i)
            #pragma unroll
            for (int reg = 0; reg < 4; ++reg)
                m = fmaxf(m, acc[i][j][reg]);
        m = fmaxf(m, __shfl_xor(m, 16, 64));
        m = fmaxf(m, __shfl_xor(m, 32, 64));
        if (quad == 0) redB[(wc * 64 + j * 16 + ln15) * 2 + wr] = m;
    }
    __syncthreads();
    if (tid < 256) colMaxS[tid] = fmaxf(redB[tid * 2], redB[tid * 2 + 1]);
    __syncthreads();
    #pragma unroll
    for (int j = 0; j < 4; ++j) {
        int n = wc * 64 + j * 16 + ln15;
        float cm = colMaxS[n];
        float s = 0.f;
        #pragma unroll
        for (int i = 0; i < 4; ++i)
            #pragma unroll
            for (int reg = 0; reg < 4; ++reg)
                s += __expf(acc[i][j][reg] - cm);
        s += __shfl_xor(s, 16, 64);
        s += __shfl_xor(s, 32, 64);
        if (quad == 0) redB[n * 2 + wr] = s;
    }
    __syncthreads();
    if (tid < 256) {
        float s = redB[tid * 2] + redB[tid * 2 + 1];
        colM[(a * 256 + tid) * 2 + rt] = colMaxS[tid];
        colS[(a * 256 + tid) * 2 + rt] = s;
    }
}

// ---- block-wide reductions over 256 threads ----
__device__ __forceinline__ float blk_max(float v, float* sm) {
    #pragma unroll
    for (int d = 1; d < 64; d <<= 1) v = fmaxf(v, __shfl_xor(v, d, 64));
    __syncthreads();
    if ((threadIdx.x & 63) == 0) sm[threadIdx.x >> 6] = v;
    __syncthreads();
    return fmaxf(fmaxf(sm[0], sm[1]), fmaxf(sm[2], sm[3]));
}
__device__ __forceinline__ float blk_sum(float v, float* sm) {
    #pragma unroll
    for (int d = 1; d < 64; d <<= 1) v += __shfl_xor(v, d, 64);
    __syncthreads();
    if ((threadIdx.x & 63) == 0) sm[threadIdx.x >> 6] = v;
    __syncthreads();
    return sm[0] + sm[1] + sm[2] + sm[3];
}

// =====================================================================
// K2: per-index LSE combine + last-block final reduction
// =====================================================================
__global__ void combine_final(const float* __restrict__ rowM, const float* __restrict__ rowS,
                              const float* __restrict__ colM, const float* __restrict__ colS,
                              const float* __restrict__ diag,
                              float* __restrict__ m123, uint* __restrict__ counter,
                              float* __restrict__ out) {
    __shared__ float sm[4];
    __shared__ uint isLast;
    int b = blockIdx.x, t = threadIdx.x;
    // M1[b] = LSE over r of (rowM[b,r], rowS[b,r])
    float m = rowM[b * 256 + t], s = rowS[b * 256 + t];
    float M = blk_max(m, sm);
    float S = blk_sum(s * __expf(m - M), sm);
    float M1 = M + __logf(S);
    // M2[b] = LSE over a of (rowM[a,b], rowS[a,b])
    m = rowM[t * 256 + b]; s = rowS[t * 256 + b];
    M = blk_max(m, sm);
    S = blk_sum(s * __expf(m - M), sm);
    float M2 = M + __logf(S);
    // M3[b] = LSE over (a, rt) of colM/colS[a, b, rt]
    float am = colM[(t * 256 + b) * 2 + 0], av = colS[(t * 256 + b) * 2 + 0];
    float bm = colM[(t * 256 + b) * 2 + 1], bv = colS[(t * 256 + b) * 2 + 1];
    m = fmaxf(am, bm);
    s = av * __expf(am - m) + bv * __expf(bm - m);
    M = blk_max(m, sm);
    S = blk_sum(s * __expf(m - M), sm);
    float M3 = M + __logf(S);
    if (t == 0) {
        m123[b] = M1 + M2 + M3;
        __threadfence();                      // release m123[b] before the flag
        isLast = (atomicAdd(counter, 1u) == 255u) ? 1u : 0u;
    }
    __syncthreads();
    if (isLast) {
        __threadfence();                      // acquire
        const volatile float* vm = (const volatile float*)m123;   // bypass L1
        const volatile float* vd = (const volatile float*)diag;
        float S1 = blk_sum(vm[t], sm);
        float S2 = blk_sum(vd[t], sm);
        if (t == 0) out[0] = S1 / 768.0f - S2 / 256.0f;
    }
}

extern "C" void kernel_launch(void* const* d_in, const int* in_sizes, int n_in,
                              void* d_out, int out_size, void* d_ws, size_t ws_size,
                              hipStream_t stream) {
    const float* x = (const float*)d_in[0];
    const float* y = (const float*)d_in[1];
    const float* z = (const float*)d_in[2];
    char* w = (char*)d_ws;
    float* rowM = (float*)(w);                   // 262144 B
    float* rowS = (float*)(w + 262144);          // 262144 B
    float* colM = (float*)(w + 524288);          // 524288 B
    float* colS = (float*)(w + 1048576);         // 524288 B
    float* diag = (float*)(w + 1572864);         // 1024 B
    float* m123 = (float*)(w + 1573888);         // 1024 B
    uint*  counter = (uint*)(w + 1574912);       // 4 B
    float* out  = (float*)d_out;

    gemm_fused<<<512, 512, 0, stream>>>(x, y, z, rowM, rowS, colM, colS, diag, counter);
    combine_final<<<256, 256, 0, stream>>>(rowM, rowS, colM, colS, diag, m123, counter, out);
}

// Round 3
// 101.014 us; speedup vs baseline: 1.0283x; 1.0283x over previous
//
#include <hip/hip_runtime.h>

#define DIM 512
#define BK 32
#define ASTRIDE 40   // ushorts per A-row: 32 payload + 8 pad -> 80B, kills bank conflicts

typedef unsigned int uint;
typedef unsigned short ushort;
typedef __attribute__((ext_vector_type(8))) short short8;
typedef __attribute__((ext_vector_type(4))) float f32x4;

// Pack two fp32 -> two bf16 (round-to-nearest-ish via +0x8000, then byte-perm pack).
__device__ __forceinline__ uint pack_bf16(float a, float b) {
    union { float f; uint u; } ua, ub;
    ua.f = a; ub.f = b;
    uint x0 = ua.u + 0x8000u;
    uint x1 = ub.u + 0x8000u;
    return __builtin_amdgcn_perm(x1, x0, 0x07060302);
}

// ---- convert z (256x512 fp32) to bf16 once ----
__global__ void zconv_kernel(const float* __restrict__ z, ushort* __restrict__ zb) {
    int t = blockIdx.x * 256 + threadIdx.x;   // 16384 threads * 8 elems = 131072
    int f = t * 8;
    float4 a = *(const float4*)(z + f);
    float4 b = *(const float4*)(z + f + 4);
    uint4 o;
    o.x = pack_bf16(a.x, a.y);
    o.y = pack_bf16(a.z, a.w);
    o.z = pack_bf16(b.x, b.y);
    o.w = pack_bf16(b.z, b.w);
    *(uint4*)(zb + f) = o;
}

// =====================================================================
// K2: fused diag + batched GEMM + LSE partials
// block = (a, rt): computes T[a, rt*128:(rt+1)*128, 0:256]
// 512 threads = 8 waves; wave (wr, wc) owns a 64x64 sub-tile (4x4 MFMA tiles)
// B staged by async global_load_lds in swizzled slot order:
//   pos(row, kc) = row*4 + ((kc + (row>>1)) & 3)   (16B slots; kc = k-chunk of 8 bf16)
// -> DMA writes lane-contiguous (required), frag reads 2-way max (free).
// =====================================================================
__global__ void __launch_bounds__(512, 4)
gemm_fused(const float* __restrict__ x, const float* __restrict__ y,
           const ushort* __restrict__ zb, const float* __restrict__ z,
           float* __restrict__ rowM, float* __restrict__ rowS,
           float* __restrict__ colM, float* __restrict__ colS,
           float* __restrict__ diag, uint* __restrict__ counter) {
    __shared__ __align__(16) float xs[DIM];
    __shared__ __align__(16) ushort As[128 * ASTRIDE];
    __shared__ __align__(16) ushort Bs[256 * BK];      // 1024 slots x 16B, swizzled
    __shared__ float redA[128 * 4];
    __shared__ float rowMaxS[128];
    __shared__ float redB[256 * 2];
    __shared__ float colMaxS[256];
    __shared__ float dred[8];

    const int tid = threadIdx.x;
    const int a   = blockIdx.x >> 1;
    const int rt  = blockIdx.x & 1;

    if (blockIdx.x == 0 && tid == 0) *counter = 0u;   // reset K3's flag each call

    xs[tid] = x[a * DIM + tid];   // x[a,:] cached for the whole block

    const int lane = tid & 63;
    const int wave = tid >> 6;
    const int quad = lane >> 4;
    const int ln15 = lane & 15;
    const int wr = wave >> 2;     // 0..1  -> row offset wr*64
    const int wc = wave & 3;      // 0..3  -> col offset wc*64

    // ---- fused diag: T[a,a,a] exact fp32 (rt==0 blocks only; D==512==blockDim) ----
    if (rt == 0) {
        float p = xs[tid] * y[a * DIM + tid] * z[a * DIM + tid];
        #pragma unroll
        for (int m = 1; m < 64; m <<= 1) p += __shfl_xor(p, m, 64);
        if (lane == 0) dred[wave] = p;
        __syncthreads();
        if (tid == 0) {
            float s = 0.f;
            #pragma unroll
            for (int w2 = 0; w2 < 8; ++w2) s += dred[w2];
            diag[a] = s;
        }
    }

    f32x4 acc[4][4];
    #pragma unroll
    for (int i = 0; i < 4; ++i)
        #pragma unroll
        for (int j = 0; j < 4; ++j)
            acc[i][j] = (f32x4){0.f, 0.f, 0.f, 0.f};

    // A staging coords: 8 bf16 per thread
    const int rA = tid >> 2;            // 0..127
    const int kA = (tid & 3) * 8;       // 0,8,16,24
    const float* yrow = y + (rt * 128 + rA) * DIM + kA;

    // B DMA coords: 2 slots per thread; slot s -> row = s>>2, kc = ((s&3)-(row>>1))&3
    const int s0 = wave * 128 + lane;
    const int row0 = s0 >> 2, kc0 = ((s0 & 3) - (row0 >> 1)) & 3;
    const ushort* gB0 = zb + row0 * DIM + kc0 * 8;
    const int s1 = s0 + 64;
    const int row1 = s1 >> 2, kc1 = ((s1 & 3) - (row1 >> 1)) & 3;
    const ushort* gB1 = zb + row1 * DIM + kc1 * 8;

    for (int kt = 0; kt < DIM / BK; ++kt) {
        const int k0 = kt * BK;
        __syncthreads();
        // async B DMA first (overlaps with A pack below)
        __builtin_amdgcn_global_load_lds(
            (const __attribute__((address_space(1))) void*)(gB0 + k0),
            (__attribute__((address_space(3))) void*)(Bs + wave * 1024), 16, 0, 0);
        __builtin_amdgcn_global_load_lds(
            (const __attribute__((address_space(1))) void*)(gB1 + k0),
            (__attribute__((address_space(3))) void*)(Bs + wave * 1024 + 512), 16, 0, 0);
        // stage A = bf16(x[a,k] * y[r,k])
        {
            float4 y0 = *(const float4*)(yrow + k0);
            float4 y1 = *(const float4*)(yrow + k0 + 4);
            float4 x0 = *(const float4*)(xs + k0 + kA);
            float4 x1 = *(const float4*)(xs + k0 + kA + 4);
            uint4 o;
            o.x = pack_bf16(y0.x * x0.x, y0.y * x0.y);
            o.y = pack_bf16(y0.z * x0.z, y0.w * x0.w);
            o.z = pack_bf16(y1.x * x1.x, y1.y * x1.y);
            o.w = pack_bf16(y1.z * x1.z, y1.w * x1.w);
            *(uint4*)(As + rA * ASTRIDE + kA) = o;
        }
        __syncthreads();
        // fragments + MFMA
        short8 af[4], bfr[4];
        #pragma unroll
        for (int i = 0; i < 4; ++i)
            af[i] = *(const short8*)(As + (wr * 64 + i * 16 + ln15) * ASTRIDE + quad * 8);
        #pragma unroll
        for (int j = 0; j < 4; ++j) {
            int row = wc * 64 + j * 16 + ln15;
            int pos = row * 4 + ((quad + (row >> 1)) & 3);
            bfr[j] = *(const short8*)(Bs + pos * 8);
        }
        #pragma unroll
        for (int i = 0; i < 4; ++i)
            #pragma unroll
            for (int j = 0; j < 4; ++j)
                acc[i][j] = __builtin_amdgcn_mfma_f32_16x16x32_bf16(af[i], bfr[j], acc[i][j], 0, 0, 0);
    }
    __syncthreads();

    // ===== row-wise LSE partials (reduce over all 256 cols s) =====
    // lane owns rows r = wr*64 + i*16 + quad*4 + reg, cols n = wc*64 + j*16 + ln15
    #pragma unroll
    for (int i = 0; i < 4; ++i) {
        #pragma unroll
        for (int reg = 0; reg < 4; ++reg) {
            float m = fmaxf(fmaxf(acc[i][0][reg], acc[i][1][reg]),
                            fmaxf(acc[i][2][reg], acc[i][3][reg]));
            #pragma unroll
            for (int d = 1; d < 16; d <<= 1) m = fmaxf(m, __shfl_xor(m, d, 64));
            if (ln15 == 0) redA[(wr * 64 + i * 16 + quad * 4 + reg) * 4 + wc] = m;
        }
    }
    __syncthreads();
    if (tid < 128) {
        float m = fmaxf(fmaxf(redA[tid * 4 + 0], redA[tid * 4 + 1]),
                        fmaxf(redA[tid * 4 + 2], redA[tid * 4 + 3]));
        rowMaxS[tid] = m;
    }
    __syncthreads();
    #pragma unroll
    for (int i = 0; i < 4; ++i) {
        #pragma unroll
        for (int reg = 0; reg < 4; ++reg) {
            int r = wr * 64 + i * 16 + quad * 4 + reg;
            float rm = rowMaxS[r];
            float s = __expf(acc[i][0][reg] - rm) + __expf(acc[i][1][reg] - rm)
                    + __expf(acc[i][2][reg] - rm) + __expf(acc[i][3][reg] - rm);
            #pragma unroll
            for (int d = 1; d < 16; d <<= 1) s += __shfl_xor(s, d, 64);
            if (ln15 == 0) redA[r * 4 + wc] = s;
        }
    }
    __syncthreads();
    if (tid < 128) {
        float s = redA[tid * 4 + 0] + redA[tid * 4 + 1] + redA[tid * 4 + 2] + redA[tid * 4 + 3];
        int rg = rt * 128 + tid;
        rowM[a * 256 + rg] = rowMaxS[tid];
        rowS[a * 256 + rg] = s;
    }

    // ===== col-wise LSE partials (reduce over this block's 128 rows) =====
    #pragma unroll
    for (int j = 0; j < 4; ++j) {
        float m = -3.4e38f;
        #pragma unroll
        for (int i = 0; i < 4; ++i)
            #pragma unroll
            for (int reg = 0; reg < 4; ++reg)
                m = fmaxf(m, acc[i][j][reg]);
        m = fmaxf(m, __shfl_xor(m, 16, 64));
        m = fmaxf(m, __shfl_xor(m, 32, 64));
        if (quad == 0) redB[(wc * 64 + j * 16 + ln15) * 2 + wr] = m;
    }
    __syncthreads();
    if (tid < 256) colMaxS[tid] = fmaxf(redB[tid * 2], redB[tid * 2 + 1]);
    __syncthreads();
    #pragma unroll
    for (int j = 0; j < 4; ++j) {
        int n = wc * 64 + j * 16 + ln15;
        float cm = colMaxS[n];
        float s = 0.f;
        #pragma unroll
        for (int i = 0; i < 4; ++i)
            #pragma unroll
            for (int reg = 0; reg < 4; ++reg)
                s += __expf(acc[i][j][reg] - cm);
        s += __shfl_xor(s, 16, 64);
        s += __shfl_xor(s, 32, 64);
        if (quad == 0) redB[n * 2 + wr] = s;
    }
    __syncthreads();
    if (tid < 256) {
        float s = redB[tid * 2] + redB[tid * 2 + 1];
        colM[(a * 256 + tid) * 2 + rt] = colMaxS[tid];
        colS[(a * 256 + tid) * 2 + rt] = s;
    }
}

// ---- block-wide reductions over 256 threads ----
__device__ __forceinline__ float blk_max(float v, float* sm) {
    #pragma unroll
    for (int d = 1; d < 64; d <<= 1) v = fmaxf(v, __shfl_xor(v, d, 64));
    __syncthreads();
    if ((threadIdx.x & 63) == 0) sm[threadIdx.x >> 6] = v;
    __syncthreads();
    return fmaxf(fmaxf(sm[0], sm[1]), fmaxf(sm[2], sm[3]));
}
__device__ __forceinline__ float blk_sum(float v, float* sm) {
    #pragma unroll
    for (int d = 1; d < 64; d <<= 1) v += __shfl_xor(v, d, 64);
    __syncthreads();
    if ((threadIdx.x & 63) == 0) sm[threadIdx.x >> 6] = v;
    __syncthreads();
    return sm[0] + sm[1] + sm[2] + sm[3];
}

// =====================================================================
// K3: per-index LSE combine + last-block final reduction
// =====================================================================
__global__ void combine_final(const float* __restrict__ rowM, const float* __restrict__ rowS,
                              const float* __restrict__ colM, const float* __restrict__ colS,
                              const float* __restrict__ diag,
                              float* __restrict__ m123, uint* __restrict__ counter,
                              float* __restrict__ out) {
    __shared__ float sm[4];
    __shared__ uint isLast;
    int b = blockIdx.x, t = threadIdx.x;
    // M1[b] = LSE over r of (rowM[b,r], rowS[b,r])
    float m = rowM[b * 256 + t], s = rowS[b * 256 + t];
    float M = blk_max(m, sm);
    float S = blk_sum(s * __expf(m - M), sm);
    float M1 = M + __logf(S);
    // M2[b] = LSE over a of (rowM[a,b], rowS[a,b])
    m = rowM[t * 256 + b]; s = rowS[t * 256 + b];
    M = blk_max(m, sm);
    S = blk_sum(s * __expf(m - M), sm);
    float M2 = M + __logf(S);
    // M3[b] = LSE over (a, rt) of colM/colS[a, b, rt]
    float am = colM[(t * 256 + b) * 2 + 0], av = colS[(t * 256 + b) * 2 + 0];
    float bm = colM[(t * 256 + b) * 2 + 1], bv = colS[(t * 256 + b) * 2 + 1];
    m = fmaxf(am, bm);
    s = av * __expf(am - m) + bv * __expf(bm - m);
    M = blk_max(m, sm);
    S = blk_sum(s * __expf(m - M), sm);
    float M3 = M + __logf(S);
    if (t == 0) {
        m123[b] = M1 + M2 + M3;
        __threadfence();                      // release m123[b] before the flag
        isLast = (atomicAdd(counter, 1u) == 255u) ? 1u : 0u;
    }
    __syncthreads();
    if (isLast) {
        __threadfence();                      // acquire
        const volatile float* vm = (const volatile float*)m123;   // bypass stale cache
        const volatile float* vd = (const volatile float*)diag;
        float S1 = blk_sum(vm[t], sm);
        float S2 = blk_sum(vd[t], sm);
        if (t == 0) out[0] = S1 / 768.0f - S2 / 256.0f;
    }
}

extern "C" void kernel_launch(void* const* d_in, const int* in_sizes, int n_in,
                              void* d_out, int out_size, void* d_ws, size_t ws_size,
                              hipStream_t stream) {
    const float* x = (const float*)d_in[0];
    const float* y = (const float*)d_in[1];
    const float* z = (const float*)d_in[2];
    char* w = (char*)d_ws;
    ushort* zb  = (ushort*)(w);                  // 262144 B
    float* rowM = (float*)(w + 262144);          // 262144 B
    float* rowS = (float*)(w + 524288);          // 262144 B
    float* colM = (float*)(w + 786432);          // 524288 B
    float* colS = (float*)(w + 1310720);         // 524288 B
    float* diag = (float*)(w + 1835008);         // 1024 B
    float* m123 = (float*)(w + 1836032);         // 1024 B
    uint*  counter = (uint*)(w + 1837056);       // 4 B
    float* out  = (float*)d_out;

    zconv_kernel<<<64, 256, 0, stream>>>(z, zb);
    gemm_fused<<<512, 512, 0, stream>>>(x, y, zb, z, rowM, rowS, colM, colS, diag, counter);
    combine_final<<<256, 256, 0, stream>>>(rowM, rowS, colM, colS, diag, m123, counter, out);
}

// Round 4
// 99.222 us; speedup vs baseline: 1.0469x; 1.0181x over previous
//
#include <hip/hip_runtime.h>

#define DIM 512
#define BK 32
#define ASTRIDE 40   // ushorts per A-row: 32 payload + 8 pad (80B) -> conflict-free frag reads

typedef unsigned int uint;
typedef unsigned short ushort;
typedef __attribute__((ext_vector_type(8))) short short8;
typedef __attribute__((ext_vector_type(4))) float f32x4;

#define GLOAD_LDS(g, l) __builtin_amdgcn_global_load_lds( \
    (const __attribute__((address_space(1))) void*)(g), \
    (__attribute__((address_space(3))) void*)(l), 16, 0, 0)

// Pack two fp32 -> two bf16 (round-to-nearest-ish via +0x8000, then byte-perm pack).
__device__ __forceinline__ uint pack_bf16(float a, float b) {
    union { float f; uint u; } ua, ub;
    ua.f = a; ub.f = b;
    uint x0 = ua.u + 0x8000u;
    uint x1 = ub.u + 0x8000u;
    return __builtin_amdgcn_perm(x1, x0, 0x07060302);
}

// ---- convert z (256x512 fp32) to bf16 once ----
__global__ void zconv_kernel(const float* __restrict__ z, ushort* __restrict__ zb) {
    int t = blockIdx.x * 256 + threadIdx.x;
    int f = t * 8;
    float4 a = *(const float4*)(z + f);
    float4 b = *(const float4*)(z + f + 4);
    uint4 o;
    o.x = pack_bf16(a.x, a.y);
    o.y = pack_bf16(a.z, a.w);
    o.z = pack_bf16(b.x, b.y);
    o.w = pack_bf16(b.z, b.w);
    *(uint4*)(zb + f) = o;
}

// =====================================================================
// K2: fused diag + batched GEMM + LSE partials, software-pipelined.
// block = (a, rt): computes T[a, rt*128:(rt+1)*128, 0:256]
// 512 threads = 8 waves; wave (wr, wc) owns a 64x64 sub-tile (4x4 MFMA tiles)
// Double-buffered LDS; ONE barrier per ktile; B-tile DMA for kt+1 and the
// y-register prefetch for kt+2 are in flight across the entire compute
// phase of kt, so the vmcnt(0) drain at the barrier is cheap.
// B slot swizzle: pos(row,kc) = row*4 + ((kc + (row>>1)) & 3)  (16B slots)
// =====================================================================
__global__ void __launch_bounds__(512, 4)
gemm_fused(const float* __restrict__ x, const float* __restrict__ y,
           const ushort* __restrict__ zb, const float* __restrict__ z,
           float* __restrict__ rowM, float* __restrict__ rowS,
           float* __restrict__ colM, float* __restrict__ colS,
           float* __restrict__ diag, uint* __restrict__ counter) {
    __shared__ __align__(16) float xs[DIM];
    __shared__ __align__(16) ushort As[2][128 * ASTRIDE];
    __shared__ __align__(16) ushort Bs[2][256 * BK];
    __shared__ float redA[128 * 4];
    __shared__ float rowMaxS[128];
    __shared__ float redB[256 * 2];
    __shared__ float colMaxS[256];
    __shared__ float dred[8];

    const int tid = threadIdx.x;
    const int a   = blockIdx.x >> 1;
    const int rt  = blockIdx.x & 1;

    if (blockIdx.x == 0 && tid == 0) *counter = 0u;   // reset K3's flag each call

    xs[tid] = x[a * DIM + tid];

    const int lane = tid & 63;
    const int wave = tid >> 6;
    const int quad = lane >> 4;
    const int ln15 = lane & 15;
    const int wr = wave >> 2;
    const int wc = wave & 3;

    // ---- fused diag: T[a,a,a] exact fp32 (rt==0 blocks only) ----
    if (rt == 0) {
        float p = xs[tid] * y[a * DIM + tid] * z[a * DIM + tid];
        #pragma unroll
        for (int m = 1; m < 64; m <<= 1) p += __shfl_xor(p, m, 64);
        if (lane == 0) dred[wave] = p;
        __syncthreads();
        if (tid == 0) {
            float s = 0.f;
            #pragma unroll
            for (int w2 = 0; w2 < 8; ++w2) s += dred[w2];
            diag[a] = s;
        }
    }
    __syncthreads();   // xs visible to all (also covers rt==1 blocks)

    f32x4 acc[4][4];
    #pragma unroll
    for (int i = 0; i < 4; ++i)
        #pragma unroll
        for (int j = 0; j < 4; ++j)
            acc[i][j] = (f32x4){0.f, 0.f, 0.f, 0.f};

    // A staging coords: 8 bf16 per thread
    const int rA = tid >> 2;            // 0..127
    const int kA = (tid & 3) * 8;       // 0,8,16,24
    const float* yrow = y + (rt * 128 + rA) * DIM + kA;

    // B DMA coords: 2 slots/thread; slot s -> row = s>>2, kc = ((s&3)-(row>>1))&3
    const int s0 = wave * 128 + lane;
    const int row0 = s0 >> 2, kc0 = ((s0 & 3) - (row0 >> 1)) & 3;
    const ushort* gB0 = zb + row0 * DIM + kc0 * 8;
    const int s1 = s0 + 64;
    const int row1 = s1 >> 2, kc1 = ((s1 & 3) - (row1 >> 1)) & 3;
    const ushort* gB1 = zb + row1 * DIM + kc1 * 8;

    // ---- prologue: stage tile 0, prefetch y[1] ----
    GLOAD_LDS(gB0, &Bs[0][wave * 1024]);
    GLOAD_LDS(gB1, &Bs[0][wave * 1024 + 512]);
    float4 ya = *(const float4*)(yrow);
    float4 yb = *(const float4*)(yrow + 4);
    {
        float4 x0 = *(const float4*)(xs + kA);
        float4 x1 = *(const float4*)(xs + kA + 4);
        uint4 o;
        o.x = pack_bf16(ya.x * x0.x, ya.y * x0.y);
        o.y = pack_bf16(ya.z * x0.z, ya.w * x0.w);
        o.z = pack_bf16(yb.x * x1.x, yb.y * x1.y);
        o.w = pack_bf16(yb.z * x1.z, yb.w * x1.w);
        *(uint4*)(&As[0][rA * ASTRIDE + kA]) = o;
    }
    ya = *(const float4*)(yrow + 32);
    yb = *(const float4*)(yrow + 36);

    #pragma unroll 2
    for (int kt = 0; kt < 16; ++kt) {
        const int cur = kt & 1, nxt = cur ^ 1;
        __syncthreads();   // As[cur]/Bs[cur] ready; drains in-flight prefetches
        if (kt < 15) {     // launch B DMA for kt+1 into the other buffer
            GLOAD_LDS(gB0 + (kt + 1) * 32, &Bs[nxt][wave * 1024]);
            GLOAD_LDS(gB1 + (kt + 1) * 32, &Bs[nxt][wave * 1024 + 512]);
        }
        short8 af[4], bfr[4];
        #pragma unroll
        for (int i = 0; i < 4; ++i)
            af[i] = *(const short8*)(&As[cur][(wr * 64 + i * 16 + ln15) * ASTRIDE + quad * 8]);
        #pragma unroll
        for (int j = 0; j < 4; ++j) {
            int row = wc * 64 + j * 16 + ln15;
            int pos = row * 4 + ((quad + (row >> 1)) & 3);
            bfr[j] = *(const short8*)(&Bs[cur][pos * 8]);
        }
        #pragma unroll
        for (int i = 0; i < 4; ++i)
            #pragma unroll
            for (int j = 0; j < 4; ++j)
                acc[i][j] = __builtin_amdgcn_mfma_f32_16x16x32_bf16(af[i], bfr[j], acc[i][j], 0, 0, 0);
        if (kt < 15) {     // pack A for kt+1 from prefetched y regs
            const int k1 = (kt + 1) * 32;
            float4 x0 = *(const float4*)(xs + k1 + kA);
            float4 x1 = *(const float4*)(xs + k1 + kA + 4);
            uint4 o;
            o.x = pack_bf16(ya.x * x0.x, ya.y * x0.y);
            o.y = pack_bf16(ya.z * x0.z, ya.w * x0.w);
            o.z = pack_bf16(yb.x * x1.x, yb.y * x1.y);
            o.w = pack_bf16(yb.z * x1.z, yb.w * x1.w);
            *(uint4*)(&As[nxt][rA * ASTRIDE + kA]) = o;
            if (kt < 14) {  // prefetch y for kt+2
                ya = *(const float4*)(yrow + (kt + 2) * 32);
                yb = *(const float4*)(yrow + (kt + 2) * 32 + 4);
            }
        }
    }
    __syncthreads();

    // ===== row-wise LSE partials (reduce over all 256 cols s) =====
    #pragma unroll
    for (int i = 0; i < 4; ++i) {
        #pragma unroll
        for (int reg = 0; reg < 4; ++reg) {
            float m = fmaxf(fmaxf(acc[i][0][reg], acc[i][1][reg]),
                            fmaxf(acc[i][2][reg], acc[i][3][reg]));
            #pragma unroll
            for (int d = 1; d < 16; d <<= 1) m = fmaxf(m, __shfl_xor(m, d, 64));
            if (ln15 == 0) redA[(wr * 64 + i * 16 + quad * 4 + reg) * 4 + wc] = m;
        }
    }
    __syncthreads();
    if (tid < 128) {
        float m = fmaxf(fmaxf(redA[tid * 4 + 0], redA[tid * 4 + 1]),
                        fmaxf(redA[tid * 4 + 2], redA[tid * 4 + 3]));
        rowMaxS[tid] = m;
    }
    __syncthreads();
    #pragma unroll
    for (int i = 0; i < 4; ++i) {
        #pragma unroll
        for (int reg = 0; reg < 4; ++reg) {
            int r = wr * 64 + i * 16 + quad * 4 + reg;
            float rm = rowMaxS[r];
            float s = __expf(acc[i][0][reg] - rm) + __expf(acc[i][1][reg] - rm)
                    + __expf(acc[i][2][reg] - rm) + __expf(acc[i][3][reg] - rm);
            #pragma unroll
            for (int d = 1; d < 16; d <<= 1) s += __shfl_xor(s, d, 64);
            if (ln15 == 0) redA[r * 4 + wc] = s;
        }
    }
    __syncthreads();
    if (tid < 128) {
        float s = redA[tid * 4 + 0] + redA[tid * 4 + 1] + redA[tid * 4 + 2] + redA[tid * 4 + 3];
        int rg = rt * 128 + tid;
        rowM[a * 256 + rg] = rowMaxS[tid];
        rowS[a * 256 + rg] = s;
    }

    // ===== col-wise LSE partials (reduce over this block's 128 rows) =====
    #pragma unroll
    for (int j = 0; j < 4; ++j) {
        float m = -3.4e38f;
        #pragma unroll
        for (int i = 0; i < 4; ++i)
            #pragma unroll
            for (int reg = 0; reg < 4; ++reg)
                m = fmaxf(m, acc[i][j][reg]);
        m = fmaxf(m, __shfl_xor(m, 16, 64));
        m = fmaxf(m, __shfl_xor(m, 32, 64));
        if (quad == 0) redB[(wc * 64 + j * 16 + ln15) * 2 + wr] = m;
    }
    __syncthreads();
    if (tid < 256) colMaxS[tid] = fmaxf(redB[tid * 2], redB[tid * 2 + 1]);
    __syncthreads();
    #pragma unroll
    for (int j = 0; j < 4; ++j) {
        int n = wc * 64 + j * 16 + ln15;
        float cm = colMaxS[n];
        float s = 0.f;
        #pragma unroll
        for (int i = 0; i < 4; ++i)
            #pragma unroll
            for (int reg = 0; reg < 4; ++reg)
                s += __expf(acc[i][j][reg] - cm);
        s += __shfl_xor(s, 16, 64);
        s += __shfl_xor(s, 32, 64);
        if (quad == 0) redB[n * 2 + wr] = s;
    }
    __syncthreads();
    if (tid < 256) {
        float s = redB[tid * 2] + redB[tid * 2 + 1];
        colM[(a * 256 + tid) * 2 + rt] = colMaxS[tid];
        colS[(a * 256 + tid) * 2 + rt] = s;
    }
}

// ---- block-wide reductions over 256 threads ----
__device__ __forceinline__ float blk_max(float v, float* sm) {
    #pragma unroll
    for (int d = 1; d < 64; d <<= 1) v = fmaxf(v, __shfl_xor(v, d, 64));
    __syncthreads();
    if ((threadIdx.x & 63) == 0) sm[threadIdx.x >> 6] = v;
    __syncthreads();
    return fmaxf(fmaxf(sm[0], sm[1]), fmaxf(sm[2], sm[3]));
}
__device__ __forceinline__ float blk_sum(float v, float* sm) {
    #pragma unroll
    for (int d = 1; d < 64; d <<= 1) v += __shfl_xor(v, d, 64);
    __syncthreads();
    if ((threadIdx.x & 63) == 0) sm[threadIdx.x >> 6] = v;
    __syncthreads();
    return sm[0] + sm[1] + sm[2] + sm[3];
}

// =====================================================================
// K3: per-index LSE combine + last-block final reduction
// =====================================================================
__global__ void combine_final(const float* __restrict__ rowM, const float* __restrict__ rowS,
                              const float* __restrict__ colM, const float* __restrict__ colS,
                              const float* __restrict__ diag,
                              float* __restrict__ m123, uint* __restrict__ counter,
                              float* __restrict__ out) {
    __shared__ float sm[4];
    __shared__ uint isLast;
    int b = blockIdx.x, t = threadIdx.x;
    float m = rowM[b * 256 + t], s = rowS[b * 256 + t];
    float M = blk_max(m, sm);
    float S = blk_sum(s * __expf(m - M), sm);
    float M1 = M + __logf(S);
    m = rowM[t * 256 + b]; s = rowS[t * 256 + b];
    M = blk_max(m, sm);
    S = blk_sum(s * __expf(m - M), sm);
    float M2 = M + __logf(S);
    float am = colM[(t * 256 + b) * 2 + 0], av = colS[(t * 256 + b) * 2 + 0];
    float bm = colM[(t * 256 + b) * 2 + 1], bv = colS[(t * 256 + b) * 2 + 1];
    m = fmaxf(am, bm);
    s = av * __expf(am - m) + bv * __expf(bm - m);
    M = blk_max(m, sm);
    S = blk_sum(s * __expf(m - M), sm);
    float M3 = M + __logf(S);
    if (t == 0) {
        m123[b] = M1 + M2 + M3;
        __threadfence();
        isLast = (atomicAdd(counter, 1u) == 255u) ? 1u : 0u;
    }
    __syncthreads();
    if (isLast) {
        __threadfence();
        const volatile float* vm = (const volatile float*)m123;
        const volatile float* vd = (const volatile float*)diag;
        float S1 = blk_sum(vm[t], sm);
        float S2 = blk_sum(vd[t], sm);
        if (t == 0) out[0] = S1 / 768.0f - S2 / 256.0f;
    }
}

extern "C" void kernel_launch(void* const* d_in, const int* in_sizes, int n_in,
                              void* d_out, int out_size, void* d_ws, size_t ws_size,
                              hipStream_t stream) {
    const float* x = (const float*)d_in[0];
    const float* y = (const float*)d_in[1];
    const float* z = (const float*)d_in[2];
    char* w = (char*)d_ws;
    ushort* zb  = (ushort*)(w);                  // 262144 B
    float* rowM = (float*)(w + 262144);          // 262144 B
    float* rowS = (float*)(w + 524288);          // 262144 B
    float* colM = (float*)(w + 786432);          // 524288 B
    float* colS = (float*)(w + 1310720);         // 524288 B
    float* diag = (float*)(w + 1835008);         // 1024 B
    float* m123 = (float*)(w + 1836032);         // 1024 B
    uint*  counter = (uint*)(w + 1837056);       // 4 B
    float* out  = (float*)d_out;

    zconv_kernel<<<64, 256, 0, stream>>>(z, zb);
    gemm_fused<<<512, 512, 0, stream>>>(x, y, zb, z, rowM, rowS, colM, colS, diag, counter);
    combine_final<<<256, 256, 0, stream>>>(rowM, rowS, colM, colS, diag, m123, counter, out);
}